// Round 3
// baseline (299.895 us; speedup 1.0000x reference)
//
#include <hip/hip_runtime.h>
#include <hip/hip_bf16.h>
#include <cstdint>
#include <cstddef>

typedef __bf16 bf16_t;
typedef __bf16 bf16x4 __attribute__((ext_vector_type(4)));
typedef __bf16 bf16x8 __attribute__((ext_vector_type(8)));
typedef float  f32x4  __attribute__((ext_vector_type(4)));

#define NB   16
#define NC   256
#define NO   256
#define SD   512
#define NPIX 4096   // 64*64
#define CPAD 40     // B LDS stride (elems): 80B -> 8-lane phases hit 32 distinct
                    // banks; 16B-aligned so bfr is one ds_read_b128

// workspace layout (bytes)
#define WS_S   0        // s   [16][256] f32  (16 KB)
#define WS_D   16384    // (unused now)
#define WS_WSQ 32768    // wsq [256][256] f32 (256 KB)
#define WS_WT  294912   // wT  [9][256][256] bf16 (1.125 MB)

// ---------------------------------------------------------------------------
// prep1: blocks 0..15  -> s[b,i]   = style[b,:] . mod_w[i,:] + mod_b[i]
//        blocks 16..271-> wsq[o,i] = sum_t w[o,i,t]^2 ; wT[t][o][i] = bf16(w[o][i][t])
// ---------------------------------------------------------------------------
__global__ __launch_bounds__(256) void prep1(
    const float* __restrict__ style, const float* __restrict__ weight,
    const float* __restrict__ mod_w, const float* __restrict__ mod_b,
    float* __restrict__ s_buf, float* __restrict__ wsq, bf16_t* __restrict__ wT)
{
    const int blk = blockIdx.x;
    const int tid = threadIdx.x;
    if (blk < 16) {
        const int b = blk, i = tid;
        const float* st = style + b * SD;
        const float* mw = mod_w + i * SD;
        float acc = 0.f;
        for (int k = 0; k < SD; k += 4) {
            float4 a = *(const float4*)(st + k);
            float4 c = *(const float4*)(mw + k);
            acc += a.x * c.x + a.y * c.y + a.z * c.z + a.w * c.w;
        }
        s_buf[b * NC + i] = acc + mod_b[i];
    } else {
        const int o = blk - 16, i = tid;
        const float* wp = weight + (o * NC + i) * 9;
        float q = 0.f;
        #pragma unroll
        for (int t = 0; t < 9; ++t) {
            float v = wp[t];
            q += v * v;
            wT[t * (NO * NC) + o * NC + i] = (bf16_t)v;
        }
        wsq[o * NC + i] = q;
    }
}

// ---------------------------------------------------------------------------
// conv: implicit-GEMM, per batch:  C[o,p] = sum_{tap,ic} wT[tap][o][ic] * xs[...]
// Block: 128 out_ch x 128 positions (2 image rows); 4 waves, each 64x64 via
// 4x4 frags of mfma_f32_16x16x32_bf16.
//
// A (weights): NO LDS. Loaded straight to VGPRs in 3-TAP GROUPS (12 frags,
//   one kh row per group), double-buffered in registers: 48 MFMAs (~230 cyc)
//   between a group's load-issue and first use -> L2 latency covered (round-1
//   failed with 1-tap groups: 78 cyc < ~400 cyc latency).
// B (x*s): fp32->bf16 reg-staged into LDS, double-buffered per channel chunk,
//   ONE barrier per chunk (9 total). CPAD=40 -> single b128 frag reads.
// d (demod): computed in the epilogue from L2-resident wsq (prep2 kernel and
//   its launch removed).
// ---------------------------------------------------------------------------
__global__ __launch_bounds__(256, 2) void conv_mfma(
    const float* __restrict__ x,
    const bf16_t* __restrict__ wT,
    const float* __restrict__ s_buf,
    const float* __restrict__ wsq,
    float* __restrict__ out)
{
    __shared__ bf16_t lds_b[2][4 * 64 * CPAD];   // 2 x 20 KB, B double buffer

    const int tid   = threadIdx.x;
    const int lane  = tid & 63;
    const int wv    = tid >> 6;
    const int wo    = wv >> 1;       // wave o-half
    const int wp    = wv & 1;        // wave p-half (= image row within tile)
    const int pt    = blockIdx.x;    // 0..31 position tiles (2 rows each)
    const int o0    = blockIdx.y * 128;
    const int batch = blockIdx.z;
    const int row0  = pt * 2;

    const int l15 = lane & 15;
    const int k0  = (lane >> 4) * 8;

    const int colB = tid & 63;       // staging: column
    const int cgrp = tid >> 6;       // staging: channel group (8 ch each)

    f32x4 acc[4][4];
    #pragma unroll
    for (int i = 0; i < 4; ++i)
        #pragma unroll
        for (int j = 0; j < 4; ++j) {
            f32x4 z = {0.f, 0.f, 0.f, 0.f};
            acc[i][j] = z;
        }

    bf16x8 bzero;
    #pragma unroll
    for (int j = 0; j < 8; ++j) bzero[j] = (bf16_t)0.f;

    // B staging: global x (fp32) -> regs (one 32-load batch) -> scale -> bf16
    // -> LDS b128 writes.
    auto STAGE = [&](int ic0, bf16_t* __restrict__ dst) {
        const float* sp = s_buf + batch * NC + ic0 + cgrp * 8;
        float4 sa = *(const float4*)sp;
        float4 sb = *(const float4*)(sp + 4);
        float sv[8] = {sa.x, sa.y, sa.z, sa.w, sb.x, sb.y, sb.z, sb.w};
        const float* xbase = x + (size_t)(batch * NC + ic0 + cgrp * 8) * NPIX + colB;
        float v[4][8];
        #pragma unroll
        for (int r = 0; r < 4; ++r) {
            const int gy = row0 - 1 + r;
            const bool valid = ((unsigned)gy < 64u);   // block-uniform
            const float* rp = xbase + gy * 64;
            #pragma unroll
            for (int j = 0; j < 8; ++j)
                v[r][j] = valid ? rp[j * NPIX] : 0.f;
        }
        #pragma unroll
        for (int r = 0; r < 4; ++r) {
            union { bf16_t h[8]; uint4 u; } pk;
            #pragma unroll
            for (int j = 0; j < 8; ++j)
                pk.h[j] = (bf16_t)(v[r][j] * sv[j]);
            *(uint4*)&dst[(r * 64 + colB) * CPAD + cgrp * 8] = pk.u;  // 16B aligned
        }
    };

    const size_t TSTR = (size_t)NO * NC;  // 65536 elements per tap plane
    // per-lane A row base: o-row (o0 + wo*64 + l15), k-slice k0
    const bf16_t* aBase = wT + (size_t)(o0 + wo * 64 + l15) * NC + k0;

    bf16x8 af0[12], af1[12];   // two 3-tap A groups (12 frags = 48 VGPR each)

    // load one 3-tap group (taps t0..t0+2 given by base) into dst regs
    auto LOADG = [&](bf16x8* dst, const bf16_t* base) {
        #pragma unroll
        for (int t = 0; t < 3; ++t)
            #pragma unroll
            for (int of = 0; of < 4; ++of)
                dst[t * 4 + of] = *(const bf16x8*)(base + (size_t)t * TSTR + of * 16 * NC);
    };

    // compute one 3-tap group (kh = group index) against B in bbuf
    auto COMPG = [&](const bf16x8* a, const bf16_t* __restrict__ bbuf, int kh) {
        const int r = wp + kh;
        #pragma unroll
        for (int kw = 0; kw < 3; ++kw) {
            bf16x8 bfr[4];
            #pragma unroll
            for (int nf = 0; nf < 4; ++nf) {
                const int c = nf * 16 + l15 + kw - 1;
                if ((unsigned)c < 64u)
                    bfr[nf] = *(const bf16x8*)&lds_b[0][0 * 0] // placeholder avoided
                        , bfr[nf] = *(const bf16x8*)&bbuf[(r * 64 + c) * CPAD + k0];
                else
                    bfr[nf] = bzero;                   // horizontal zero-pad
            }
            #pragma unroll
            for (int of = 0; of < 4; ++of)
                #pragma unroll
                for (int nf = 0; nf < 4; ++nf)
                    acc[of][nf] = __builtin_amdgcn_mfma_f32_16x16x32_bf16(
                        a[kw * 4 + of], bfr[nf], acc[of][nf], 0, 0, 0);
        }
    };

    // one chunk: A0 holds this chunk's G0 on entry; on exit A0 holds next
    // chunk's G0. Loads for the NEXT group are issued before computing the
    // CURRENT one (48 MFMAs of cover).
    auto CHUNK = [&](int chunk, bf16x8* A0, bf16x8* A1,
                     const bf16_t* __restrict__ bbuf, bf16_t* __restrict__ bnext) {
        if (chunk < 7) STAGE((chunk + 1) * 32, bnext);
        const bf16_t* aC = aBase + chunk * 32;
        const bf16_t* aN = aBase + (chunk < 7 ? (chunk + 1) : chunk) * 32;
        LOADG(A1, aC + 3 * TSTR);  COMPG(A0, bbuf, 0);
        LOADG(A0, aC + 6 * TSTR);  COMPG(A1, bbuf, 1);
        LOADG(A1, aN);             COMPG(A0, bbuf, 2);
        __syncthreads();
        // NOTE: caller must swap roles: next chunk's G0 is in A1
    };

    // prologue
    LOADG(af0, aBase);              // chunk 0, taps 0..2
    STAGE(0, &lds_b[0][0]);
    __syncthreads();

    #pragma unroll 1
    for (int c2 = 0; c2 < 4; ++c2) {
        CHUNK(2 * c2,     af0, af1, &lds_b[0][0], &lds_b[1][0]);
        // after even chunk, next G0 sits in af1
        CHUNK(2 * c2 + 1, af1, af0, &lds_b[1][0], &lds_b[0][0]);
        // after odd chunk, next G0 sits in af0
    }

    // ---- demod d for this block's 128 o's (replaces prep2 kernel) ----
    // thread pair (2*ol, 2*ol+1) splits the 256-ch sum in half
    float* d_sh = (float*)&lds_b[0][0];      // LDS free after last barrier
    {
        const int ol   = tid >> 1;
        const int half = tid & 1;
        const float* wq = wsq + (size_t)(o0 + ol) * NC + half * 128;
        const float* sb = s_buf + batch * NC + half * 128;
        float sum = 0.f;
        #pragma unroll 4
        for (int i = 0; i < 128; i += 4) {
            float4 w4 = *(const float4*)(wq + i);
            float4 s4 = *(const float4*)(sb + i);
            sum += w4.x * s4.x * s4.x + w4.y * s4.y * s4.y
                 + w4.z * s4.z * s4.z + w4.w * s4.w * s4.w;
        }
        sum += __shfl_xor(sum, 1);
        if (half == 0) d_sh[ol] = rsqrtf(sum + 1e-8f);
    }
    __syncthreads();

    // ---- epilogue: y = acc * d[b,o], store fp32 ----
    const int p_base = pt * 128 + wp * 64;
    #pragma unroll
    for (int of = 0; of < 4; ++of) {
        #pragma unroll
        for (int rg = 0; rg < 4; ++rg) {
            const int o_l = wo * 64 + of * 16 + (lane >> 4) * 4 + rg;
            const float dv = d_sh[o_l];
            const size_t obase = (size_t)(batch * NO + o0 + o_l) * NPIX;
            #pragma unroll
            for (int nf = 0; nf < 4; ++nf) {
                const int p_g = p_base + nf * 16 + l15;
                out[obase + p_g] = acc[of][nf][rg] * dv;
            }
        }
    }
}

// ---------------------------------------------------------------------------
extern "C" void kernel_launch(void* const* d_in, const int* in_sizes, int n_in,
                              void* d_out, int out_size, void* d_ws, size_t ws_size,
                              hipStream_t stream)
{
    const float* x      = (const float*)d_in[0];
    const float* style  = (const float*)d_in[1];
    const float* weight = (const float*)d_in[2];
    const float* mod_w  = (const float*)d_in[3];
    const float* mod_b  = (const float*)d_in[4];
    float* out = (float*)d_out;

    char* ws = (char*)d_ws;
    float*  s_buf = (float*)(ws + WS_S);
    float*  wsq   = (float*)(ws + WS_WSQ);
    bf16_t* wT    = (bf16_t*)(ws + WS_WT);

    hipLaunchKernelGGL(prep1, dim3(272), dim3(256), 0, stream,
                       style, weight, mod_w, mod_b, s_buf, wsq, wT);
    hipLaunchKernelGGL(conv_mfma, dim3(32, 2, 16), dim3(256), 0, stream,
                       x, wT, s_buf, wsq, out);
}

// Round 4
// 235.106 us; speedup vs baseline: 1.2756x; 1.2756x over previous
//
#include <hip/hip_runtime.h>
#include <hip/hip_bf16.h>
#include <cstdint>
#include <cstddef>

typedef __bf16 bf16_t;
typedef __bf16 bf16x4 __attribute__((ext_vector_type(4)));
typedef __bf16 bf16x8 __attribute__((ext_vector_type(8)));
typedef float  f32x4  __attribute__((ext_vector_type(4)));

#define NB   16
#define NC   256
#define NO   256
#define SD   512
#define NPIX 4096   // 64*64
#define CPAD 36     // B LDS stride: 72B rows -> 8B ops are conflict-free (r1: 0 cycles)

// workspace layout (bytes)
#define WS_S   0        // s   [16][256] f32  (16 KB)
#define WS_WSQ 32768    // wsq [256][256] f32 (256 KB)
#define WS_WT  294912   // wT  [9][256][256] bf16 (1.125 MB)

// ---------------------------------------------------------------------------
// prep1: blocks 0..15  -> s[b,i]   = style[b,:] . mod_w[i,:] + mod_b[i]
//        blocks 16..271-> wsq[o,i] = sum_t w[o,i,t]^2 ; wT[t][o][i] = bf16(w[o][i][t])
// ---------------------------------------------------------------------------
__global__ __launch_bounds__(256) void prep1(
    const float* __restrict__ style, const float* __restrict__ weight,
    const float* __restrict__ mod_w, const float* __restrict__ mod_b,
    float* __restrict__ s_buf, float* __restrict__ wsq, bf16_t* __restrict__ wT)
{
    const int blk = blockIdx.x;
    const int tid = threadIdx.x;
    if (blk < 16) {
        const int b = blk, i = tid;
        const float* st = style + b * SD;
        const float* mw = mod_w + i * SD;
        float acc = 0.f;
        for (int k = 0; k < SD; k += 4) {
            float4 a = *(const float4*)(st + k);
            float4 c = *(const float4*)(mw + k);
            acc += a.x * c.x + a.y * c.y + a.z * c.z + a.w * c.w;
        }
        s_buf[b * NC + i] = acc + mod_b[i];
    } else {
        const int o = blk - 16, i = tid;
        const float* wp = weight + (o * NC + i) * 9;
        float q = 0.f;
        #pragma unroll
        for (int t = 0; t < 9; ++t) {
            float v = wp[t];
            q += v * v;
            wT[t * (NO * NC) + o * NC + i] = (bf16_t)v;
        }
        wsq[o * NC + i] = q;
    }
}

// ---------------------------------------------------------------------------
// conv: implicit-GEMM. Block: 128 out_ch x 128 positions (2 image rows);
// 4 waves, each 64x64 via 4x4 frags of mfma_f32_16x16x32_bf16.
//
// A (weights): global_load_lds width=16 into a 4-deep LDS ring (kgrp-major,
//   conflict-free). DMA prefetch depth = 2 taps; per-tap RAW s_barrier with
//   COUNTED s_waitcnt vmcnt(4) -- never a full drain in the steady loop
//   (T3+T4; __syncthreads' vmcnt(0) drain was the round-0 governor).
// B (x*s): single LDS buffer, CPAD=36 + 8B ops (0 conflicts, r1-measured).
//   x-loads for the next chunk issue BEFORE the chunk barrier (latency hidden).
// d (demod): fused epilogue from L2-resident wsq (no prep2 kernel).
// ---------------------------------------------------------------------------
__device__ __forceinline__ void stage_a(const bf16_t* __restrict__ wT_tap,
                                        int o0, int ic0, bf16_t* dst, int tid)
{
    #pragma unroll
    for (int it = 0; it < 2; ++it) {
        int s = it * 256 + tid;                 // 512 16B segments
        // seg s -> (kgrp = s>>7, row = s&127); LDS dest linear (DMA rule #21)
        const bf16_t* g = wT_tap + (o0 + (s & 127)) * NC + ic0 + (s >> 7) * 8;
        __builtin_amdgcn_global_load_lds(
            (const __attribute__((address_space(1))) void*)g,
            (__attribute__((address_space(3))) void*)(dst + s * 8),
            16, 0, 0);
    }
}

__global__ __launch_bounds__(256, 2) void conv_mfma(
    const float* __restrict__ x,
    const bf16_t* __restrict__ wT,
    const float* __restrict__ s_buf,
    const float* __restrict__ wsq,
    float* __restrict__ out)
{
    __shared__ bf16_t lds_a[4][4096];           // 32 KB: 4-deep A ring, kgrp-major
    __shared__ bf16_t lds_b[4 * 64 * CPAD];     // 18 KB: B (x*s), single buffer

    const int tid   = threadIdx.x;
    const int lane  = tid & 63;
    const int wv    = tid >> 6;
    const int wo    = wv >> 1;       // wave o-half
    const int wp    = wv & 1;        // wave p-half (= image row within tile)
    const int pt    = blockIdx.x;    // 0..31 position tiles (2 rows each)
    const int o0    = blockIdx.y * 128;
    const int batch = blockIdx.z;
    const int row0  = pt * 2;

    const int l15 = lane & 15;
    const int kg  = lane >> 4;       // k-group 0..3
    const int k0  = kg * 8;

    const int colB = tid & 63;       // staging: column
    const int cgrp = tid >> 6;       // staging: channel group (8 ch each)

    f32x4 acc[4][4];
    #pragma unroll
    for (int i = 0; i < 4; ++i)
        #pragma unroll
        for (int j = 0; j < 4; ++j) {
            f32x4 z = {0.f, 0.f, 0.f, 0.f};
            acc[i][j] = z;
        }

    bf16x8 bzero;
    #pragma unroll
    for (int j = 0; j < 8; ++j) bzero[j] = (bf16_t)0.f;

    const size_t TSTR = (size_t)NO * NC;  // 65536 elems per tap plane
    bf16_t* lds_a0 = &lds_a[0][0];

    // ---- B staging split: XLOAD (issue global loads) / BWRITE (convert+LDS) ----
    float vx[4][8];
    float sv[8];
    auto XLOAD = [&](int ic0) {
        const float* sp = s_buf + batch * NC + ic0 + cgrp * 8;
        float4 sa = *(const float4*)sp;
        float4 sb = *(const float4*)(sp + 4);
        sv[0]=sa.x; sv[1]=sa.y; sv[2]=sa.z; sv[3]=sa.w;
        sv[4]=sb.x; sv[5]=sb.y; sv[6]=sb.z; sv[7]=sb.w;
        const float* xbase = x + (size_t)(batch * NC + ic0 + cgrp * 8) * NPIX + colB;
        #pragma unroll
        for (int r = 0; r < 4; ++r) {
            const int gy = row0 - 1 + r;
            const bool valid = ((unsigned)gy < 64u);   // block-uniform
            const float* rp = xbase + gy * 64;
            #pragma unroll
            for (int j = 0; j < 8; ++j)
                vx[r][j] = valid ? rp[j * NPIX] : 0.f;
        }
    };
    auto BWRITE = [&]() {
        #pragma unroll
        for (int r = 0; r < 4; ++r) {
            const int lbase = (r * 64 + colB) * CPAD + cgrp * 8;
            #pragma unroll
            for (int half = 0; half < 2; ++half) {
                union { bf16_t h[4]; uint2 u; } pk;
                #pragma unroll
                for (int j = 0; j < 4; ++j)
                    pk.h[j] = (bf16_t)(vx[r][half * 4 + j] * sv[half * 4 + j]);
                *(uint2*)&lds_b[lbase + half * 4] = pk.u;   // 8B aligned, conflict-free
            }
        }
    };

    // ---- prologue: B chunk 0; A taps 0,1 of chunk 0 ----
    XLOAD(0);
    BWRITE();                                   // no prior readers
    stage_a(wT,        o0, 0, lds_a0 + 0 * 4096, tid);   // g=0 -> buf 0
    stage_a(wT + TSTR, o0, 0, lds_a0 + 1 * 4096, tid);   // g=1 -> buf 1
    asm volatile("s_waitcnt lgkmcnt(0)" ::: "memory");
    __builtin_amdgcn_sched_barrier(0);
    __builtin_amdgcn_s_barrier();

    #pragma unroll 1
    for (int chunk = 0; chunk < 8; ++chunk) {
        const int ic0 = chunk * 32;
        // buffer index for tap g=9*chunk+tap is (chunk+tap)&3  (9 ≡ 1 mod 4)

        #pragma unroll
        for (int tap = 0; tap < 9; ++tap) {
            bf16_t* nbuf = lds_a0 + (size_t)((chunk + tap + 2) & 3) * 4096;
            if (tap < 7) {
                // prefetch tap+2 of this chunk
                stage_a(wT + (size_t)(tap + 2) * TSTR, o0, ic0, nbuf, tid);
                asm volatile("s_waitcnt vmcnt(4)" ::: "memory");
            } else if (chunk < 7) {
                // taps 7,8 prefetch next chunk's taps 0,1
                stage_a(wT + (size_t)(tap - 7) * TSTR, o0, ic0 + 32, nbuf, tid);
                asm volatile("s_waitcnt vmcnt(4)" ::: "memory");
            } else if (tap == 7) {
                asm volatile("s_waitcnt vmcnt(2)" ::: "memory");
            } else {
                asm volatile("s_waitcnt vmcnt(0)" ::: "memory");
            }
            __builtin_amdgcn_sched_barrier(0);
            __builtin_amdgcn_s_barrier();       // raw: all waves' A[g] landed;
                                                // prev-tap reads are complete

            const bf16_t* abuf = lds_a0 + (size_t)((chunk + tap) & 3) * 4096;
            const int kh = tap / 3, kw = tap % 3;

            bf16x8 af[4];
            #pragma unroll
            for (int of = 0; of < 4; ++of)
                af[of] = *(const bf16x8*)&abuf[kg * 1024 + (wo * 64 + of * 16 + l15) * 8];

            const int r = wp + kh;
            bf16x8 bfr[4];
            #pragma unroll
            for (int nf = 0; nf < 4; ++nf) {
                const int c = nf * 16 + l15 + kw - 1;
                if ((unsigned)c < 64u) {
                    const bf16_t* p = &lds_b[(r * 64 + c) * CPAD + k0];
                    bf16x4 lo = *(const bf16x4*)p;
                    bf16x4 hi = *(const bf16x4*)(p + 4);
                    bfr[nf] = __builtin_shufflevector(lo, hi, 0, 1, 2, 3, 4, 5, 6, 7);
                } else {
                    bfr[nf] = bzero;             // horizontal zero-pad
                }
            }

            #pragma unroll
            for (int of = 0; of < 4; ++of)
                #pragma unroll
                for (int nf = 0; nf < 4; ++nf)
                    acc[of][nf] = __builtin_amdgcn_mfma_f32_16x16x32_bf16(
                        af[of], bfr[nf], acc[of][nf], 0, 0, 0);
        }

        if (chunk < 7) {
            // next chunk's B: issue loads BEFORE the barrier (latency hidden
            // under barrier spread), convert+write after.
            XLOAD(ic0 + 32);
            __builtin_amdgcn_sched_barrier(0);
            __builtin_amdgcn_s_barrier();       // all waves done reading lds_b
            BWRITE();
            asm volatile("s_waitcnt lgkmcnt(0)" ::: "memory");
            __builtin_amdgcn_sched_barrier(0);
            __builtin_amdgcn_s_barrier();       // lds_b ready; A DMAs stay in flight
        }
    }

    // ---- demod d for this block's 128 o's (fused prep2) ----
    __syncthreads();                            // lds_b reads done; full drain ok here
    float* d_sh = (float*)&lds_b[0];
    {
        const int ol   = tid >> 1;
        const int half = tid & 1;
        const float* wq = wsq + (size_t)(o0 + ol) * NC + half * 128;
        const float* sb = s_buf + batch * NC + half * 128;
        float sum = 0.f;
        #pragma unroll 4
        for (int i = 0; i < 128; i += 4) {
            float4 w4 = *(const float4*)(wq + i);
            float4 s4 = *(const float4*)(sb + i);
            sum += w4.x * s4.x * s4.x + w4.y * s4.y * s4.y
                 + w4.z * s4.z * s4.z + w4.w * s4.w * s4.w;
        }
        sum += __shfl_xor(sum, 1);
        if (half == 0) d_sh[ol] = rsqrtf(sum + 1e-8f);
    }
    __syncthreads();

    // ---- epilogue: y = acc * d[b,o], store fp32 ----
    const int p_base = pt * 128 + wp * 64;
    #pragma unroll
    for (int of = 0; of < 4; ++of) {
        #pragma unroll
        for (int rg = 0; rg < 4; ++rg) {
            const int o_l = wo * 64 + of * 16 + (lane >> 4) * 4 + rg;
            const float dv = d_sh[o_l];
            const size_t obase = (size_t)(batch * NO + o0 + o_l) * NPIX;
            #pragma unroll
            for (int nf = 0; nf < 4; ++nf) {
                const int p_g = p_base + nf * 16 + l15;
                out[obase + p_g] = acc[of][nf][rg] * dv;
            }
        }
    }
}

// ---------------------------------------------------------------------------
extern "C" void kernel_launch(void* const* d_in, const int* in_sizes, int n_in,
                              void* d_out, int out_size, void* d_ws, size_t ws_size,
                              hipStream_t stream)
{
    const float* x      = (const float*)d_in[0];
    const float* style  = (const float*)d_in[1];
    const float* weight = (const float*)d_in[2];
    const float* mod_w  = (const float*)d_in[3];
    const float* mod_b  = (const float*)d_in[4];
    float* out = (float*)d_out;

    char* ws = (char*)d_ws;
    float*  s_buf = (float*)(ws + WS_S);
    float*  wsq   = (float*)(ws + WS_WSQ);
    bf16_t* wT    = (bf16_t*)(ws + WS_WT);

    hipLaunchKernelGGL(prep1, dim3(272), dim3(256), 0, stream,
                       style, weight, mod_w, mod_b, s_buf, wsq, wT);
    hipLaunchKernelGGL(conv_mfma, dim3(32, 2, 16), dim3(256), 0, stream,
                       x, wT, s_buf, wsq, out);
}